// Round 20
// baseline (467.044 us; speedup 1.0000x reference)
//
#include <hip/hip_runtime.h>
#include <hip/hip_bf16.h>
#include <math.h>

#define B_ 32
#define S_ 2048
#define D_ 1024
#define TEMP_ 9.0f

typedef __attribute__((ext_vector_type(8))) short short8;
typedef __attribute__((ext_vector_type(4))) float f32x4;
typedef __attribute__((ext_vector_type(4))) unsigned short ushort4v;

__device__ __forceinline__ unsigned short f2b(float f) {
  union { float f; unsigned int u; } v; v.f = f;
  unsigned int r = v.u;
  r += 0x7fffu + ((r >> 16) & 1u);   // RNE
  return (unsigned short)(r >> 16);
}
__device__ __forceinline__ float b2f(unsigned short b) {
  union { float f; unsigned int u; } v; v.u = ((unsigned int)b) << 16;
  return v.f;
}
// packed f32x2 -> bf16x2, single VALU op
__device__ __forceinline__ unsigned cvtpk(float a, float b) {
  unsigned r;
  asm("v_cvt_pk_bf16_f32 %0, %1, %2" : "=v"(r) : "v"(a), "v"(b));
  return r;
}
// fast tanh: 1 - 2/(e^2x + 1); saturates correctly at +-inf
__device__ __forceinline__ float tanh_fast(float x) {
  float ez = __expf(2.f * x);
  return 1.f - __fdividef(2.f, ez + 1.f);
}

// ---------------- K_pack_w1: W1 f32 -> bf16 fragment-major ----------------
// w1t chunk c = (cg*32 + kt)*64 + l holds W1[col = cg*16 + (l&15)][k = kt*32 + (l>>4)*8 + j]
__global__ void k_pack_w1(const float* __restrict__ W1, unsigned short* __restrict__ w1t) {
  int c = blockIdx.x * 256 + threadIdx.x;   // [0, 131072)
  int l  = c & 63;
  int kt = (c >> 6) & 31;
  int cg = c >> 11;
  int col = cg * 16 + (l & 15);
  int k0  = kt * 32 + (l >> 4) * 8;
  const float* src = W1 + (size_t)col * D_ + k0;
  float4 x0 = *reinterpret_cast<const float4*>(src);
  float4 x1 = *reinterpret_cast<const float4*>(src + 4);
  uint4 w;
  w.x = f2b(x0.x) | ((unsigned)f2b(x0.y) << 16);
  w.y = f2b(x0.z) | ((unsigned)f2b(x0.w) << 16);
  w.z = f2b(x1.x) | ((unsigned)f2b(x1.y) << 16);
  w.w = f2b(x1.z) | ((unsigned)f2b(x1.w) << 16);
  reinterpret_cast<uint4*>(w1t)[c] = w;
}

// ---------------- K0: tdot[b] = h_t[b]·Wm_t + bmap ----------------
__global__ void k0_tdot(const float* __restrict__ h_t, const float* __restrict__ Wmap,
                        const float* __restrict__ bmap, float* __restrict__ tdot) {
  int b = blockIdx.x;
  int t = threadIdx.x;
  float p = 0.f;
  for (int k = t; k < D_; k += 256) p += h_t[b*D_ + k] * Wmap[D_ + k];
  __shared__ float red[256];
  red[t] = p; __syncthreads();
  for (int off = 128; off > 0; off >>= 1) { if (t < off) red[t] += red[t+off]; __syncthreads(); }
  if (t == 0) tdot[b] = red[0] + bmap[0];
}

// ---------------- K1 (fallback-only standalone gate) ----------------
__global__ void k1_gate(const float* __restrict__ aux, const float* __restrict__ Wmap,
                        const float* __restrict__ noise, const float* __restrict__ tdot,
                        float* __restrict__ Gout) {
  int w = (blockIdx.x * 256 + threadIdx.x) >> 6;
  int lane = threadIdx.x & 63;
  const float4* arow = reinterpret_cast<const float4*>(aux + (size_t)w * D_);
  const float4* wrow = reinterpret_cast<const float4*>(Wmap);
  float p = 0.f;
  for (int it = 0; it < 4; ++it) {
    float4 a = arow[it*64 + lane];
    float4 m = wrow[it*64 + lane];
    p += a.x*m.x + a.y*m.y + a.z*m.z + a.w*m.w;
  }
  for (int msk = 32; msk > 0; msk >>= 1) p += __shfl_xor(p, msk);
  if (lane == 0) {
    int b = w >> 11;
    float logits = p + tdot[b];
    float u = noise[w];
    u = fminf(fmaxf(u, 1e-7f), 1.f - 1e-7f);
    float logistic = logf(u) - log1pf(-u);
    float x = (logits + logistic) / TEMP_;
    Gout[w] = 1.f / (1.f + expf(-x));
  }
}

// ---------------- K2: reg-staged f32 A + IN-LOOP gate (Wmap in LDS, spill-proof) --------
// e[row] = sum_col tanh(h_s·W1[col,:] + b1[col]) * W2[col]
// A: f32 h_s -> regs -> v_cvt_pk_bf16_f32 -> ds_write_b128 into the 0-conflict
//    involution layout. Double-buffered LDS (2 x 8KB). lgkmcnt(0)+barrier per tile.
// B: fragment-major w1t, ON-DEMAND (prefetch dropped to free 16 VGPR for the gate).
// Gate (r13 retry, spill-proof): 32 rows/block (8/wave), 1 aux float4/lane/tile,
//    1-tile software pipeline; Wmap dot-vector read from LDS (4KB staged once,
//    2 lanes/bank = free) instead of 16 persistent VGPRs. Net gate regs ~= +9.
//    All loads compiler-tracked; sync skeleton unchanged. Spill tripwire: WRITE_SIZE.
extern __shared__ unsigned short lds2[];  // 2 x 8KB A bufs + 4KB Wmap = 20480 B

__global__ __launch_bounds__(256, 2) void k2gt(
    const float* __restrict__ h_s, const unsigned short* __restrict__ w1t,
    const float* __restrict__ b1, const float* __restrict__ W2,
    float* __restrict__ e_buf,
    const float* __restrict__ aux, const float* __restrict__ Wmap,
    const float* __restrict__ noise, const float* __restrict__ tdot,
    float* __restrict__ Gout) {
  // T1 bijective XCD swizzle: all 4 col-chunks of a row-chunk on one XCD, consecutive.
  int bid = blockIdx.x;           // [0,2048)
  int xcd = bid & 7;
  int sub = bid >> 3;             // [0,256)
  int cc  = sub & 3;
  int rc  = xcd + 8 * (sub >> 2); // [0,512)
  int rowBase = rc * 128;
  int colBase = cc * 256;

  int t = threadIdx.x;
  int lane = t & 63;
  int wv = t >> 6;                // 4 waves; wave output 128 rows x 64 cols
  int kslot = lane >> 4;

  // A ds-read byte offsets (8 KiB buffer; involution verified 0-conflict r5..r19)
  int aOff[8];
#pragma unroll
  for (int m = 0; m < 8; ++m) {
    int r = m * 16 + (lane & 15);
    aOff[m] = r * 64 + ((kslot ^ ((r >> 1) & 3)) << 4);
  }

  // staging assignment: thread t owns chunks c0=t (r0=t>>2), c1=256+t (r1=64+(t>>2)),
  // slot_log = t&3 (8 bf16 k-values = 32B f32 per chunk).
  int r0 = t >> 2, r1 = 64 + (t >> 2);
  int sl = t & 3;
  const float* gS0 = h_s + (size_t)(rowBase + r0) * D_ + sl * 8;
  const float* gS1 = h_s + (size_t)(rowBase + r1) * D_ + sl * 8;
  int dstW0 = r0 * 64 + ((sl ^ ((r0 >> 1) & 3)) << 4);
  int dstW1 = r1 * 64 + ((sl ^ ((r1 >> 1) & 3)) << 4);

  // B fragment base pointers: wave wv covers col-groups (colBase/16 + wv*4 + n)
  const unsigned short* pB[4];
#pragma unroll
  for (int n = 0; n < 4; ++n) {
    int cg = (colBase >> 4) + wv * 4 + n;
    pB[n] = w1t + (size_t)cg * 16384 + lane * 8;
  }

  // gate state: 8 rows/wave, 1 float4/lane/tile, 1-tile pipeline; Wmap lives in LDS.
  char* wmLDS = (char*)lds2 + 16384;
  int rowG = (bid << 5) | (wv << 3);
  const float* gAux = aux + ((size_t)rowG << 10) + (lane << 2);
  float4 gbuf;
  float gacc = 0.f;

#define GATE_FIN(I) do {                                                       \
    float p = gacc;                                                            \
    for (int msk = 32; msk > 0; msk >>= 1) p += __shfl_xor(p, msk);            \
    if (lane == 0) {                                                           \
      int row = rowG + (I);                                                    \
      float logits = p + tdot[row >> 11];                                      \
      float u = noise[row];                                                    \
      u = fminf(fmaxf(u, 1e-7f), 1.f - 1e-7f);                                 \
      float logistic = logf(u) - log1pf(-u);                                   \
      float x = (logits + logistic) / TEMP_;                                   \
      Gout[row] = 1.f / (1.f + expf(-x));                                      \
    }                                                                          \
    gacc = 0.f;                                                                \
  } while (0)

#define GATE_STEP(T) do {                                                      \
    if ((T) >= 1) {                                                            \
      int pr = (T) - 1;                                                        \
      f32x4 wm = *reinterpret_cast<const f32x4*>(wmLDS + ((pr & 3) << 10) + (lane << 4)); \
      gacc += gbuf.x*wm[0] + gbuf.y*wm[1] + gbuf.z*wm[2] + gbuf.w*wm[3];       \
      if ((pr & 3) == 3) GATE_FIN(pr >> 2);                                    \
    }                                                                          \
    gbuf = *reinterpret_cast<const float4*>(gAux + (((T) >> 2) << 10) + (((T) & 3) << 8)); \
  } while (0)

  f32x4 acc[8][4] = {};
  float4 sA0, sA1, sA2, sA3;      // staged f32 for one tile (16 VGPR, named: rule 20)

#define LOADF(TT) do {                                                         \
    sA0 = *reinterpret_cast<const float4*>(gS0 + (TT) * 32);                   \
    sA1 = *reinterpret_cast<const float4*>(gS0 + (TT) * 32 + 4);               \
    sA2 = *reinterpret_cast<const float4*>(gS1 + (TT) * 32);                   \
    sA3 = *reinterpret_cast<const float4*>(gS1 + (TT) * 32 + 4);               \
  } while (0)

#define CVT_WRITE(TT) do {                                                     \
    char* _bw = (char*)lds2 + ((TT) & 1) * 8192;                               \
    uint4 w0, w1;                                                              \
    w0.x = cvtpk(sA0.x, sA0.y); w0.y = cvtpk(sA0.z, sA0.w);                    \
    w0.z = cvtpk(sA1.x, sA1.y); w0.w = cvtpk(sA1.z, sA1.w);                    \
    w1.x = cvtpk(sA2.x, sA2.y); w1.y = cvtpk(sA2.z, sA2.w);                    \
    w1.z = cvtpk(sA3.x, sA3.y); w1.w = cvtpk(sA3.z, sA3.w);                    \
    *reinterpret_cast<uint4*>(_bw + dstW0) = w0;                               \
    *reinterpret_cast<uint4*>(_bw + dstW1) = w1;                               \
  } while (0)

  // per tile: {ds_read A(T) | B(T) on-demand | cvt+write A(T+1) | load A(T+2) |
  //            gate step (consume T-1, load T) | MFMA | lgkm0+bar}
#define K2_TILE(T, DO_W, DO_L) do {                                            \
    const char* _ab = (const char*)lds2 + ((T) & 1) * 8192;                    \
    short8 af[8], bf[4];                                                       \
    _Pragma("unroll")                                                          \
    for (int m = 0; m < 8; ++m)                                                \
      af[m] = *reinterpret_cast<const short8*>(_ab + aOff[m]);                 \
    _Pragma("unroll")                                                          \
    for (int n = 0; n < 4; ++n)                                                \
      bf[n] = *reinterpret_cast<const short8*>(pB[n] + (T) * 512);             \
    if (DO_W) CVT_WRITE((T) + 1);                                              \
    if (DO_L) LOADF((T) + 2);                                                  \
    GATE_STEP(T);                                                              \
    __builtin_amdgcn_s_setprio(1);                                             \
    _Pragma("unroll")                                                          \
    for (int m = 0; m < 8; ++m)                                                \
      _Pragma("unroll")                                                        \
      for (int n = 0; n < 4; ++n)                                              \
        acc[m][n] = __builtin_amdgcn_mfma_f32_16x16x32_bf16(af[m], bf[n], acc[m][n], 0, 0, 0); \
    __builtin_amdgcn_s_setprio(0);                                             \
    asm volatile("s_waitcnt lgkmcnt(0)" ::: "memory");                         \
    __builtin_amdgcn_s_barrier();                                              \
  } while (0)

  // prologue: Wmap -> LDS; A(0) -> buf0; A(1) staged; publish
  reinterpret_cast<float4*>(wmLDS)[t] = reinterpret_cast<const float4*>(Wmap)[t];
  LOADF(0);
  CVT_WRITE(0);
  LOADF(1);
  asm volatile("s_waitcnt lgkmcnt(0)" ::: "memory");
  __builtin_amdgcn_s_barrier();

#pragma unroll
  for (int tt = 0; tt < 30; ++tt) K2_TILE(tt, true, true);   // LOADF covers 2..31
  K2_TILE(30, true, false);
  K2_TILE(31, false, false);
#undef K2_TILE
#undef CVT_WRITE
#undef LOADF

  // gate epilogue: consume chunk 31 (row 7, sub-chunk 3) and finalize row 7
  {
    f32x4 wm = *reinterpret_cast<const f32x4*>(wmLDS + (3 << 10) + (lane << 4));
    gacc += gbuf.x*wm[0] + gbuf.y*wm[1] + gbuf.z*wm[2] + gbuf.w*wm[3];
    GATE_FIN(7);
  }
#undef GATE_STEP
#undef GATE_FIN

  // epilogue: e-partial = sum over this block's 256 cols of tanh(pre+b1)*W2
  float b1v[4], w2v[4];
#pragma unroll
  for (int n = 0; n < 4; ++n) {
    int col = colBase + wv * 64 + n * 16 + (lane & 15);
    b1v[n] = b1[col];
    w2v[n] = W2[col];
  }
#pragma unroll
  for (int m = 0; m < 8; ++m) {
#pragma unroll
    for (int j = 0; j < 4; ++j) {
      float s = 0.f;
#pragma unroll
      for (int n = 0; n < 4; ++n)
        s += tanh_fast(acc[m][n][j] + b1v[n]) * w2v[n];
      s += __shfl_xor(s, 1);
      s += __shfl_xor(s, 2);
      s += __shfl_xor(s, 4);
      s += __shfl_xor(s, 8);
      if ((lane & 15) == 0) {
        int row = rowBase + m * 16 + ((lane >> 4) << 2) + j;
        atomicAdd(&e_buf[row], s);
      }
    }
  }
}

// ---------------- K2 fallback (f32 inputs, reg-staged conversion, 128^2) ----------------
#define BM 128
#define BN 128
#define BK 64
__global__ __launch_bounds__(256) void k2_egemm_f32(
    const float* __restrict__ h_s, const float* __restrict__ W1,
    const float* __restrict__ b1, const float* __restrict__ W2,
    float* __restrict__ e_buf) {
  __shared__ unsigned short As[BM * BK];
  __shared__ unsigned short Bs[BN * BK];
  int bid = blockIdx.x;
  int colBase = (bid & 7) * BN;
  int rowBase = (bid >> 3) * BM;
  int t = threadIdx.x;
  int lane = t & 63;
  int wave = t >> 6;
  int wr = wave >> 1, wc = wave & 1;
  f32x4 acc[4][4] = {};
  for (int k0 = 0; k0 < D_; k0 += BK) {
    __syncthreads();
    for (int i = 0; i < 4; ++i) {
      int flat = i*256 + t;
      int r = flat >> 3;
      int c8 = flat & 7;
      int byte = (r*128 + c8*16) ^ ((r & 7) << 4);
      {
        const float4* g = reinterpret_cast<const float4*>(h_s + (size_t)(rowBase + r)*D_ + k0 + c8*8);
        float4 x0 = g[0], x1 = g[1];
        uint4 w;
        w.x = f2b(x0.x) | ((unsigned)f2b(x0.y) << 16);
        w.y = f2b(x0.z) | ((unsigned)f2b(x0.w) << 16);
        w.z = f2b(x1.x) | ((unsigned)f2b(x1.y) << 16);
        w.w = f2b(x1.z) | ((unsigned)f2b(x1.w) << 16);
        *reinterpret_cast<uint4*>(reinterpret_cast<char*>(As) + byte) = w;
      }
      {
        const float4* g = reinterpret_cast<const float4*>(W1 + (size_t)(colBase + r)*D_ + k0 + c8*8);
        float4 x0 = g[0], x1 = g[1];
        uint4 w;
        w.x = f2b(x0.x) | ((unsigned)f2b(x0.y) << 16);
        w.y = f2b(x0.z) | ((unsigned)f2b(x0.w) << 16);
        w.z = f2b(x1.x) | ((unsigned)f2b(x1.y) << 16);
        w.w = f2b(x1.z) | ((unsigned)f2b(x1.w) << 16);
        *reinterpret_cast<uint4*>(reinterpret_cast<char*>(Bs) + byte) = w;
      }
    }
    __syncthreads();
    for (int kk = 0; kk < BK; kk += 32) {
      short8 af[4], bf[4];
      int kByte = kk*2 + ((lane >> 4) << 4);
      for (int m = 0; m < 4; ++m) {
        int r = wr*64 + m*16 + (lane & 15);
        int byte = (r*128 + kByte) ^ ((r & 7) << 4);
        af[m] = *reinterpret_cast<const short8*>(reinterpret_cast<const char*>(As) + byte);
      }
      for (int n = 0; n < 4; ++n) {
        int r = wc*64 + n*16 + (lane & 15);
        int byte = (r*128 + kByte) ^ ((r & 7) << 4);
        bf[n] = *reinterpret_cast<const short8*>(reinterpret_cast<const char*>(Bs) + byte);
      }
      for (int m = 0; m < 4; ++m)
        for (int n = 0; n < 4; ++n)
          acc[m][n] = __builtin_amdgcn_mfma_f32_16x16x32_bf16(af[m], bf[n], acc[m][n], 0, 0, 0);
    }
  }
  float b1v[4], w2v[4];
  for (int n = 0; n < 4; ++n) {
    int col = colBase + wc*64 + n*16 + (lane & 15);
    b1v[n] = b1[col];
    w2v[n] = W2[col];
  }
  for (int m = 0; m < 4; ++m) {
    for (int j = 0; j < 4; ++j) {
      float s = 0.f;
      for (int n = 0; n < 4; ++n)
        s += tanhf(acc[m][n][j] + b1v[n]) * w2v[n];
      s += __shfl_xor(s, 1);
      s += __shfl_xor(s, 2);
      s += __shfl_xor(s, 4);
      s += __shfl_xor(s, 8);
      if ((lane & 15) == 0) {
        int row = rowBase + wr*64 + m*16 + ((lane >> 4) << 2) + j;
        atomicAdd(&e_buf[row], s);
      }
    }
  }
}

// ---------------- K3a: v[s] = max_b e[b,s] ----------------
__global__ void k3a_vmax(const float* __restrict__ e_buf, float* __restrict__ v) {
  int s = blockIdx.x * 256 + threadIdx.x;
  if (s >= S_) return;
  float m = -1e30f;
  for (int b = 0; b < B_; ++b) m = fmaxf(m, e_buf[b*S_ + s]);
  v[s] = m;
}

// ---------------- K3b: align = exp(e-v)*G / sum_s (in-place over G) ----------------
__global__ void k3b_align(const float* __restrict__ e_buf, const float* __restrict__ v,
                          float* __restrict__ galign) {
  int b = blockIdx.x;
  int t = threadIdx.x;
  __shared__ float sc[S_];
  __shared__ float red[256];
  float p = 0.f;
  for (int s = t; s < S_; s += 256) {
    float x = expf(e_buf[b*S_ + s] - v[s]) * galign[b*S_ + s];
    sc[s] = x;
    p += x;
  }
  red[t] = p; __syncthreads();
  for (int off = 128; off > 0; off >>= 1) { if (t < off) red[t] += red[t+off]; __syncthreads(); }
  float inv = 1.f / red[0];
  for (int s = t; s < S_; s += 256) galign[b*S_ + s] = sc[s] * inv;
}

// ---------------- K4 (f32 h_s): c[b,:] = sum_s align[b,s]*h_s[b,s,:] ----------------
__global__ void k4_ctx_f32(const float* __restrict__ h_s, const float* __restrict__ align,
                           float* __restrict__ c) {
  int bid = blockIdx.x;
  int b = bid >> 6;
  int sBase = (bid & 63) * 32;
  int t = threadIdx.x;
  float4 accv = {0.f, 0.f, 0.f, 0.f};
  for (int si = 0; si < 32; ++si) {
    int s = sBase + si;
    float a = align[b*S_ + s];
    float4 hv = *reinterpret_cast<const float4*>(h_s + (size_t)(b*S_ + s)*D_ + t*4);
    accv.x += a*hv.x; accv.y += a*hv.y; accv.z += a*hv.z; accv.w += a*hv.w;
  }
  atomicAdd(&c[b*D_ + t*4 + 0], accv.x);
  atomicAdd(&c[b*D_ + t*4 + 1], accv.y);
  atomicAdd(&c[b*D_ + t*4 + 2], accv.z);
  atomicAdd(&c[b*D_ + t*4 + 3], accv.w);
}

// ---------------- K5: attn_h = tanh([c,h_t] @ Wout^T) ----------------
__global__ void k5_out(const float* __restrict__ c, const float* __restrict__ h_t,
                       const float* __restrict__ Wout, float* __restrict__ out) {
  int W = (blockIdx.x * 256 + threadIdx.x) >> 6;
  int lane = threadIdx.x & 63;
  int b = W >> 10;
  int o = W & 1023;
  const float* wrow = Wout + (size_t)o * (2 * D_);
  float p = 0.f;
  for (int it = 0; it < 16; ++it) {
    int k = it*64 + lane;
    p += c[b*D_ + k] * wrow[k];
  }
  for (int it = 16; it < 32; ++it) {
    int k = it*64 + lane;
    p += h_t[b*D_ + (k - D_)] * wrow[k];
  }
  for (int m = 32; m > 0; m >>= 1) p += __shfl_xor(p, m);
  if (lane == 0) out[b*D_ + o] = tanhf(p);
}

extern "C" void kernel_launch(void* const* d_in, const int* in_sizes, int n_in,
                              void* d_out, int out_size, void* d_ws, size_t ws_size,
                              hipStream_t stream) {
  const float* h_t   = (const float*)d_in[0];
  const float* h_s   = (const float*)d_in[1];
  const float* aux   = (const float*)d_in[2];
  const float* noise = (const float*)d_in[3];
  const float* Wmap  = (const float*)d_in[4];
  const float* bmap  = (const float*)d_in[5];
  const float* W1    = (const float*)d_in[6];
  const float* b1    = (const float*)d_in[7];
  const float* W2    = (const float*)d_in[8];
  // d_in[9] = b2: cancels exactly in exp(e-v)/sum -> unused
  const float* Wout  = (const float*)d_in[10];

  float* out    = (float*)d_out;          // [attn_h: 32768 | align: 65536]
  float* galign = out + B_*D_;            // holds G first, overwritten with align

  const size_t W1_N   = (size_t)D_*D_;      // 1M
  const size_t needed = W1_N*2 + (65536 + 32 + 2048 + 32768) * sizeof(float);

  if (ws_size >= needed) {
    unsigned short* w1t = (unsigned short*)d_ws;                   // 2 MB (fragment-major)
    float* fws   = (float*)(w1t + W1_N);
    float* e_buf = fws;                     // 65536
    float* tdot  = fws + 65536;             // 32
    float* v     = fws + 65568;             // 2048
    float* c     = fws + 67616;             // 32768

    hipMemsetAsync(e_buf, 0, 65536 * sizeof(float), stream);
    hipMemsetAsync(c, 0, 32768 * sizeof(float), stream);

    hipFuncSetAttribute(reinterpret_cast<const void*>(k2gt),
                        hipFuncAttributeMaxDynamicSharedMemorySize, 20480);

    k_pack_w1<<<512, 256, 0, stream>>>(W1, w1t);
    k0_tdot<<<32, 256, 0, stream>>>(h_t, Wmap, bmap, tdot);
    k2gt<<<2048, 256, 20480, stream>>>(h_s, w1t, b1, W2, e_buf,
                                       aux, Wmap, noise, tdot, galign);
    k3a_vmax<<<8, 256, 0, stream>>>(e_buf, v);
    k3b_align<<<32, 256, 0, stream>>>(e_buf, v, galign);
    k4_ctx_f32<<<2048, 256, 0, stream>>>(h_s, galign, c);
    k5_out<<<8192, 256, 0, stream>>>(c, h_t, Wout, out);
  } else {
    float* ws    = (float*)d_ws;
    float* e_buf = ws;                      // 65536
    float* tdot  = ws + 65536;              // 32
    float* v     = ws + 65568;              // 2048
    float* c     = ws + 67616;              // 32768

    hipMemsetAsync(e_buf, 0, 65536 * sizeof(float), stream);
    hipMemsetAsync(c, 0, 32768 * sizeof(float), stream);

    k0_tdot<<<32, 256, 0, stream>>>(h_t, Wmap, bmap, tdot);
    k1_gate<<<16384, 256, 0, stream>>>(aux, Wmap, noise, tdot, galign);
    k2_egemm_f32<<<4096, 256, 0, stream>>>(h_s, W1, b1, W2, e_buf);
    k3a_vmax<<<8, 256, 0, stream>>>(e_buf, v);
    k3b_align<<<32, 256, 0, stream>>>(e_buf, v, galign);
    k4_ctx_f32<<<2048, 256, 0, stream>>>(h_s, galign, c);
    k5_out<<<8192, 256, 0, stream>>>(c, h_t, Wout, out);
  }
}

// Round 21
// 298.237 us; speedup vs baseline: 1.5660x; 1.5660x over previous
//
#include <hip/hip_runtime.h>
#include <hip/hip_bf16.h>
#include <math.h>

#define B_ 32
#define S_ 2048
#define D_ 1024
#define TEMP_ 9.0f

typedef __attribute__((ext_vector_type(8))) short short8;
typedef __attribute__((ext_vector_type(4))) float f32x4;
typedef __attribute__((ext_vector_type(4))) unsigned short ushort4v;

__device__ __forceinline__ unsigned short f2b(float f) {
  union { float f; unsigned int u; } v; v.f = f;
  unsigned int r = v.u;
  r += 0x7fffu + ((r >> 16) & 1u);   // RNE
  return (unsigned short)(r >> 16);
}
__device__ __forceinline__ float b2f(unsigned short b) {
  union { float f; unsigned int u; } v; v.u = ((unsigned int)b) << 16;
  return v.f;
}
// packed f32x2 -> bf16x2, single VALU op
__device__ __forceinline__ unsigned cvtpk(float a, float b) {
  unsigned r;
  asm("v_cvt_pk_bf16_f32 %0, %1, %2" : "=v"(r) : "v"(a), "v"(b));
  return r;
}
// fast tanh: 1 - 2/(e^2x + 1); saturates correctly at +-inf
__device__ __forceinline__ float tanh_fast(float x) {
  float ez = __expf(2.f * x);
  return 1.f - __fdividef(2.f, ez + 1.f);
}

// ---------------- K_pack_w1: W1 f32 -> bf16 fragment-major ----------------
// w1t chunk c = (cg*32 + kt)*64 + l holds W1[col = cg*16 + (l&15)][k = kt*32 + (l>>4)*8 + j]
__global__ void k_pack_w1(const float* __restrict__ W1, unsigned short* __restrict__ w1t) {
  int c = blockIdx.x * 256 + threadIdx.x;   // [0, 131072)
  int l  = c & 63;
  int kt = (c >> 6) & 31;
  int cg = c >> 11;
  int col = cg * 16 + (l & 15);
  int k0  = kt * 32 + (l >> 4) * 8;
  const float* src = W1 + (size_t)col * D_ + k0;
  float4 x0 = *reinterpret_cast<const float4*>(src);
  float4 x1 = *reinterpret_cast<const float4*>(src + 4);
  uint4 w;
  w.x = f2b(x0.x) | ((unsigned)f2b(x0.y) << 16);
  w.y = f2b(x0.z) | ((unsigned)f2b(x0.w) << 16);
  w.z = f2b(x1.x) | ((unsigned)f2b(x1.y) << 16);
  w.w = f2b(x1.z) | ((unsigned)f2b(x1.w) << 16);
  reinterpret_cast<uint4*>(w1t)[c] = w;
}

// ---------------- K0: tdot[b] = h_t[b]·Wm_t + bmap ----------------
__global__ void k0_tdot(const float* __restrict__ h_t, const float* __restrict__ Wmap,
                        const float* __restrict__ bmap, float* __restrict__ tdot) {
  int b = blockIdx.x;
  int t = threadIdx.x;
  float p = 0.f;
  for (int k = t; k < D_; k += 256) p += h_t[b*D_ + k] * Wmap[D_ + k];
  __shared__ float red[256];
  red[t] = p; __syncthreads();
  for (int off = 128; off > 0; off >>= 1) { if (t < off) red[t] += red[t+off]; __syncthreads(); }
  if (t == 0) tdot[b] = red[0] + bmap[0];
}

// ---------------- K1 (fallback-only standalone gate) ----------------
__global__ void k1_gate(const float* __restrict__ aux, const float* __restrict__ Wmap,
                        const float* __restrict__ noise, const float* __restrict__ tdot,
                        float* __restrict__ Gout) {
  int w = (blockIdx.x * 256 + threadIdx.x) >> 6;
  int lane = threadIdx.x & 63;
  const float4* arow = reinterpret_cast<const float4*>(aux + (size_t)w * D_);
  const float4* wrow = reinterpret_cast<const float4*>(Wmap);
  float p = 0.f;
  for (int it = 0; it < 4; ++it) {
    float4 a = arow[it*64 + lane];
    float4 m = wrow[it*64 + lane];
    p += a.x*m.x + a.y*m.y + a.z*m.z + a.w*m.w;
  }
  for (int msk = 32; msk > 0; msk >>= 1) p += __shfl_xor(p, msk);
  if (lane == 0) {
    int b = w >> 11;
    float logits = p + tdot[b];
    float u = noise[w];
    u = fminf(fmaxf(u, 1e-7f), 1.f - 1e-7f);
    float logistic = logf(u) - log1pf(-u);
    float x = (logits + logistic) / TEMP_;
    Gout[w] = 1.f / (1.f + expf(-x));
  }
}

// ---------------- gate block: 32 rows (8/wave), r12-verified code ----------------
__device__ __forceinline__ void gate_rows(
    int bid, int wv, int lane,
    const float* __restrict__ aux, const float* __restrict__ Wmap,
    const float* __restrict__ noise, const float* __restrict__ tdot,
    float* __restrict__ Gout) {
  const float4* wrow = reinterpret_cast<const float4*>(Wmap);
  float4 m0 = wrow[lane], m1 = wrow[64 + lane], m2 = wrow[128 + lane], m3 = wrow[192 + lane];
  int rowG = (bid << 5) | (wv << 3);
#pragma unroll 2
  for (int i = 0; i < 8; ++i) {
    int row = rowG + i;
    const float4* arow = reinterpret_cast<const float4*>(aux + (size_t)row * D_);
    float4 a0 = arow[lane], a1 = arow[64 + lane], a2 = arow[128 + lane], a3 = arow[192 + lane];
    float p = a0.x*m0.x + a0.y*m0.y + a0.z*m0.z + a0.w*m0.w
            + a1.x*m1.x + a1.y*m1.y + a1.z*m1.z + a1.w*m1.w
            + a2.x*m2.x + a2.y*m2.y + a2.z*m2.z + a2.w*m2.w
            + a3.x*m3.x + a3.y*m3.y + a3.z*m3.z + a3.w*m3.w;
    for (int msk = 32; msk > 0; msk >>= 1) p += __shfl_xor(p, msk);
    if (lane == 0) {
      float logits = p + tdot[row >> 11];
      float u = noise[row];
      u = fminf(fmaxf(u, 1e-7f), 1.f - 1e-7f);
      float logistic = logf(u) - log1pf(-u);
      float x = (logits + logistic) / TEMP_;
      Gout[row] = 1.f / (1.f + expf(-x));
    }
  }
}

// ---------------- K2: reg-staged f32 A, B-in-reg post-MFMA prefetch, bit8-phased gate --------
// e[row] = sum_col tanh(h_s·W1[col,:] + b1[col]) * W2[col]
// A: f32 h_s -> regs -> v_cvt_pk_bf16_f32 -> ds_write_b128 into the 0-conflict
//    involution layout. Double-buffered LDS (2 x 8KB). lgkmcnt(0)+barrier per tile
//    (WAR: writes target the buffer whose readers retired at the previous barrier).
// This is the r19-verified best configuration (299 us, absmax 0.0039). In-loop gate
// variants spill (r13: WRITE 298MB, r20: 368MB) — the kernel sits at the 256-reg
// occupancy cliff; gate stays as bit8-phased pre/post phase.
extern __shared__ unsigned short lds2[];  // 2 bufs x 8 KiB = 16 KiB

__global__ __launch_bounds__(256, 2) void k2gt(
    const float* __restrict__ h_s, const unsigned short* __restrict__ w1t,
    const float* __restrict__ b1, const float* __restrict__ W2,
    float* __restrict__ e_buf,
    const float* __restrict__ aux, const float* __restrict__ Wmap,
    const float* __restrict__ noise, const float* __restrict__ tdot,
    float* __restrict__ Gout) {
  // T1 bijective XCD swizzle: all 4 col-chunks of a row-chunk on one XCD, consecutive.
  int bid = blockIdx.x;           // [0,2048)
  int xcd = bid & 7;
  int sub = bid >> 3;             // [0,256)
  int cc  = sub & 3;
  int rc  = xcd + 8 * (sub >> 2); // [0,512)
  int rowBase = rc * 128;
  int colBase = cc * 256;

  int t = threadIdx.x;
  int lane = t & 63;
  int wv = t >> 6;                // 4 waves; wave output 128 rows x 64 cols
  int kslot = lane >> 4;

  if ((bid >> 8) & 1) gate_rows(bid, wv, lane, aux, Wmap, noise, tdot, Gout);

  // A ds-read byte offsets (8 KiB buffer; involution verified 0-conflict r5..r19)
  int aOff[8];
#pragma unroll
  for (int m = 0; m < 8; ++m) {
    int r = m * 16 + (lane & 15);
    aOff[m] = r * 64 + ((kslot ^ ((r >> 1) & 3)) << 4);
  }

  // staging assignment: thread t owns chunks c0=t (r0=t>>2), c1=256+t (r1=64+(t>>2)),
  // slot_log = t&3 (8 bf16 k-values = 32B f32 per chunk).
  int r0 = t >> 2, r1 = 64 + (t >> 2);
  int sl = t & 3;
  const float* gS0 = h_s + (size_t)(rowBase + r0) * D_ + sl * 8;
  const float* gS1 = h_s + (size_t)(rowBase + r1) * D_ + sl * 8;
  int dstW0 = r0 * 64 + ((sl ^ ((r0 >> 1) & 3)) << 4);
  int dstW1 = r1 * 64 + ((sl ^ ((r1 >> 1) & 3)) << 4);

  // B fragment base pointers: wave wv covers col-groups (colBase/16 + wv*4 + n)
  const unsigned short* pB[4];
#pragma unroll
  for (int n = 0; n < 4; ++n) {
    int cg = (colBase >> 4) + wv * 4 + n;
    pB[n] = w1t + (size_t)cg * 16384 + lane * 8;
  }

  f32x4 acc[8][4] = {};
  float4 sA0, sA1, sA2, sA3;      // staged f32 for one tile (16 VGPR, named: rule 20)
  short8 bf[4];                   // persistent B fragments (prefetched 1 tile ahead)

#define LOADF(TT) do {                                                         \
    sA0 = *reinterpret_cast<const float4*>(gS0 + (TT) * 32);                   \
    sA1 = *reinterpret_cast<const float4*>(gS0 + (TT) * 32 + 4);               \
    sA2 = *reinterpret_cast<const float4*>(gS1 + (TT) * 32);                   \
    sA3 = *reinterpret_cast<const float4*>(gS1 + (TT) * 32 + 4);               \
  } while (0)

#define CVT_WRITE(TT) do {                                                     \
    char* _bw = (char*)lds2 + ((TT) & 1) * 8192;                               \
    uint4 w0, w1;                                                              \
    w0.x = cvtpk(sA0.x, sA0.y); w0.y = cvtpk(sA0.z, sA0.w);                    \
    w0.z = cvtpk(sA1.x, sA1.y); w0.w = cvtpk(sA1.z, sA1.w);                    \
    w1.x = cvtpk(sA2.x, sA2.y); w1.y = cvtpk(sA2.z, sA2.w);                    \
    w1.z = cvtpk(sA3.x, sA3.y); w1.w = cvtpk(sA3.z, sA3.w);                    \
    *reinterpret_cast<uint4*>(_bw + dstW0) = w0;                               \
    *reinterpret_cast<uint4*>(_bw + dstW1) = w1;                               \
  } while (0)

  // per tile: {ds_read A(T) | cvt+write A(T+1) | load A(T+2) | MFMA(af,bf=B(T)) |
  //            prefetch bf=B(T+1) | lgkm0+bar}
#define K2_TILE(T, DO_W, DO_L, DO_B) do {                                      \
    const char* _ab = (const char*)lds2 + ((T) & 1) * 8192;                    \
    short8 af[8];                                                              \
    _Pragma("unroll")                                                          \
    for (int m = 0; m < 8; ++m)                                                \
      af[m] = *reinterpret_cast<const short8*>(_ab + aOff[m]);                 \
    if (DO_W) CVT_WRITE((T) + 1);                                              \
    if (DO_L) LOADF((T) + 2);                                                  \
    __builtin_amdgcn_s_setprio(1);                                             \
    _Pragma("unroll")                                                          \
    for (int m = 0; m < 8; ++m)                                                \
      _Pragma("unroll")                                                        \
      for (int n = 0; n < 4; ++n)                                              \
        acc[m][n] = __builtin_amdgcn_mfma_f32_16x16x32_bf16(af[m], bf[n], acc[m][n], 0, 0, 0); \
    __builtin_amdgcn_s_setprio(0);                                             \
    if (DO_B) {                                                                \
      _Pragma("unroll")                                                        \
      for (int n = 0; n < 4; ++n)                                              \
        bf[n] = *reinterpret_cast<const short8*>(pB[n] + ((T) + 1) * 512);     \
    }                                                                          \
    asm volatile("s_waitcnt lgkmcnt(0)" ::: "memory");                         \
    __builtin_amdgcn_s_barrier();                                              \
  } while (0)

  // prologue: B(0) early (max latency cover); A(0) -> buf0; A(1) staged; publish buf0
#pragma unroll
  for (int n = 0; n < 4; ++n)
    bf[n] = *reinterpret_cast<const short8*>(pB[n]);
  LOADF(0);
  CVT_WRITE(0);
  LOADF(1);
  asm volatile("s_waitcnt lgkmcnt(0)" ::: "memory");
  __builtin_amdgcn_s_barrier();

#pragma unroll
  for (int tt = 0; tt < 30; ++tt) K2_TILE(tt, true, true, true);  // LOADF covers 2..31
  K2_TILE(30, true, false, true);
  K2_TILE(31, false, false, false);
#undef K2_TILE
#undef CVT_WRITE
#undef LOADF

  // epilogue: e-partial = sum over this block's 256 cols of tanh(pre+b1)*W2
  float b1v[4], w2v[4];
#pragma unroll
  for (int n = 0; n < 4; ++n) {
    int col = colBase + wv * 64 + n * 16 + (lane & 15);
    b1v[n] = b1[col];
    w2v[n] = W2[col];
  }
#pragma unroll
  for (int m = 0; m < 8; ++m) {
#pragma unroll
    for (int j = 0; j < 4; ++j) {
      float s = 0.f;
#pragma unroll
      for (int n = 0; n < 4; ++n)
        s += tanh_fast(acc[m][n][j] + b1v[n]) * w2v[n];
      s += __shfl_xor(s, 1);
      s += __shfl_xor(s, 2);
      s += __shfl_xor(s, 4);
      s += __shfl_xor(s, 8);
      if ((lane & 15) == 0) {
        int row = rowBase + m * 16 + ((lane >> 4) << 2) + j;
        atomicAdd(&e_buf[row], s);
      }
    }
  }

  if (!((bid >> 8) & 1)) gate_rows(bid, wv, lane, aux, Wmap, noise, tdot, Gout);
}

// ---------------- K2 fallback (f32 inputs, reg-staged conversion, 128^2) ----------------
#define BM 128
#define BN 128
#define BK 64
__global__ __launch_bounds__(256) void k2_egemm_f32(
    const float* __restrict__ h_s, const float* __restrict__ W1,
    const float* __restrict__ b1, const float* __restrict__ W2,
    float* __restrict__ e_buf) {
  __shared__ unsigned short As[BM * BK];
  __shared__ unsigned short Bs[BN * BK];
  int bid = blockIdx.x;
  int colBase = (bid & 7) * BN;
  int rowBase = (bid >> 3) * BM;
  int t = threadIdx.x;
  int lane = t & 63;
  int wave = t >> 6;
  int wr = wave >> 1, wc = wave & 1;
  f32x4 acc[4][4] = {};
  for (int k0 = 0; k0 < D_; k0 += BK) {
    __syncthreads();
    for (int i = 0; i < 4; ++i) {
      int flat = i*256 + t;
      int r = flat >> 3;
      int c8 = flat & 7;
      int byte = (r*128 + c8*16) ^ ((r & 7) << 4);
      {
        const float4* g = reinterpret_cast<const float4*>(h_s + (size_t)(rowBase + r)*D_ + k0 + c8*8);
        float4 x0 = g[0], x1 = g[1];
        uint4 w;
        w.x = f2b(x0.x) | ((unsigned)f2b(x0.y) << 16);
        w.y = f2b(x0.z) | ((unsigned)f2b(x0.w) << 16);
        w.z = f2b(x1.x) | ((unsigned)f2b(x1.y) << 16);
        w.w = f2b(x1.z) | ((unsigned)f2b(x1.w) << 16);
        *reinterpret_cast<uint4*>(reinterpret_cast<char*>(As) + byte) = w;
      }
      {
        const float4* g = reinterpret_cast<const float4*>(W1 + (size_t)(colBase + r)*D_ + k0 + c8*8);
        float4 x0 = g[0], x1 = g[1];
        uint4 w;
        w.x = f2b(x0.x) | ((unsigned)f2b(x0.y) << 16);
        w.y = f2b(x0.z) | ((unsigned)f2b(x0.w) << 16);
        w.z = f2b(x1.x) | ((unsigned)f2b(x1.y) << 16);
        w.w = f2b(x1.z) | ((unsigned)f2b(x1.w) << 16);
        *reinterpret_cast<uint4*>(reinterpret_cast<char*>(Bs) + byte) = w;
      }
    }
    __syncthreads();
    for (int kk = 0; kk < BK; kk += 32) {
      short8 af[4], bf[4];
      int kByte = kk*2 + ((lane >> 4) << 4);
      for (int m = 0; m < 4; ++m) {
        int r = wr*64 + m*16 + (lane & 15);
        int byte = (r*128 + kByte) ^ ((r & 7) << 4);
        af[m] = *reinterpret_cast<const short8*>(reinterpret_cast<const char*>(As) + byte);
      }
      for (int n = 0; n < 4; ++n) {
        int r = wc*64 + n*16 + (lane & 15);
        int byte = (r*128 + kByte) ^ ((r & 7) << 4);
        bf[n] = *reinterpret_cast<const short8*>(reinterpret_cast<const char*>(Bs) + byte);
      }
      for (int m = 0; m < 4; ++m)
        for (int n = 0; n < 4; ++n)
          acc[m][n] = __builtin_amdgcn_mfma_f32_16x16x32_bf16(af[m], bf[n], acc[m][n], 0, 0, 0);
    }
  }
  float b1v[4], w2v[4];
  for (int n = 0; n < 4; ++n) {
    int col = colBase + wc*64 + n*16 + (lane & 15);
    b1v[n] = b1[col];
    w2v[n] = W2[col];
  }
  for (int m = 0; m < 4; ++m) {
    for (int j = 0; j < 4; ++j) {
      float s = 0.f;
      for (int n = 0; n < 4; ++n)
        s += tanhf(acc[m][n][j] + b1v[n]) * w2v[n];
      s += __shfl_xor(s, 1);
      s += __shfl_xor(s, 2);
      s += __shfl_xor(s, 4);
      s += __shfl_xor(s, 8);
      if ((lane & 15) == 0) {
        int row = rowBase + wr*64 + m*16 + ((lane >> 4) << 2) + j;
        atomicAdd(&e_buf[row], s);
      }
    }
  }
}

// ---------------- K3a: v[s] = max_b e[b,s] ----------------
__global__ void k3a_vmax(const float* __restrict__ e_buf, float* __restrict__ v) {
  int s = blockIdx.x * 256 + threadIdx.x;
  if (s >= S_) return;
  float m = -1e30f;
  for (int b = 0; b < B_; ++b) m = fmaxf(m, e_buf[b*S_ + s]);
  v[s] = m;
}

// ---------------- K3b: align = exp(e-v)*G / sum_s (in-place over G) ----------------
__global__ void k3b_align(const float* __restrict__ e_buf, const float* __restrict__ v,
                          float* __restrict__ galign) {
  int b = blockIdx.x;
  int t = threadIdx.x;
  __shared__ float sc[S_];
  __shared__ float red[256];
  float p = 0.f;
  for (int s = t; s < S_; s += 256) {
    float x = expf(e_buf[b*S_ + s] - v[s]) * galign[b*S_ + s];
    sc[s] = x;
    p += x;
  }
  red[t] = p; __syncthreads();
  for (int off = 128; off > 0; off >>= 1) { if (t < off) red[t] += red[t+off]; __syncthreads(); }
  float inv = 1.f / red[0];
  for (int s = t; s < S_; s += 256) galign[b*S_ + s] = sc[s] * inv;
}

// ---------------- K4 (f32 h_s): c[b,:] = sum_s align[b,s]*h_s[b,s,:] ----------------
__global__ void k4_ctx_f32(const float* __restrict__ h_s, const float* __restrict__ align,
                           float* __restrict__ c) {
  int bid = blockIdx.x;
  int b = bid >> 6;
  int sBase = (bid & 63) * 32;
  int t = threadIdx.x;
  float4 accv = {0.f, 0.f, 0.f, 0.f};
  for (int si = 0; si < 32; ++si) {
    int s = sBase + si;
    float a = align[b*S_ + s];
    float4 hv = *reinterpret_cast<const float4*>(h_s + (size_t)(b*S_ + s)*D_ + t*4);
    accv.x += a*hv.x; accv.y += a*hv.y; accv.z += a*hv.z; accv.w += a*hv.w;
  }
  atomicAdd(&c[b*D_ + t*4 + 0], accv.x);
  atomicAdd(&c[b*D_ + t*4 + 1], accv.y);
  atomicAdd(&c[b*D_ + t*4 + 2], accv.z);
  atomicAdd(&c[b*D_ + t*4 + 3], accv.w);
}

// ---------------- K5: attn_h = tanh([c,h_t] @ Wout^T) ----------------
__global__ void k5_out(const float* __restrict__ c, const float* __restrict__ h_t,
                       const float* __restrict__ Wout, float* __restrict__ out) {
  int W = (blockIdx.x * 256 + threadIdx.x) >> 6;
  int lane = threadIdx.x & 63;
  int b = W >> 10;
  int o = W & 1023;
  const float* wrow = Wout + (size_t)o * (2 * D_);
  float p = 0.f;
  for (int it = 0; it < 16; ++it) {
    int k = it*64 + lane;
    p += c[b*D_ + k] * wrow[k];
  }
  for (int it = 16; it < 32; ++it) {
    int k = it*64 + lane;
    p += h_t[b*D_ + (k - D_)] * wrow[k];
  }
  for (int m = 32; m > 0; m >>= 1) p += __shfl_xor(p, m);
  if (lane == 0) out[b*D_ + o] = tanhf(p);
}

extern "C" void kernel_launch(void* const* d_in, const int* in_sizes, int n_in,
                              void* d_out, int out_size, void* d_ws, size_t ws_size,
                              hipStream_t stream) {
  const float* h_t   = (const float*)d_in[0];
  const float* h_s   = (const float*)d_in[1];
  const float* aux   = (const float*)d_in[2];
  const float* noise = (const float*)d_in[3];
  const float* Wmap  = (const float*)d_in[4];
  const float* bmap  = (const float*)d_in[5];
  const float* W1    = (const float*)d_in[6];
  const float* b1    = (const float*)d_in[7];
  const float* W2    = (const float*)d_in[8];
  // d_in[9] = b2: cancels exactly in exp(e-v)/sum -> unused
  const float* Wout  = (const float*)d_in[10];

  float* out    = (float*)d_out;          // [attn_h: 32768 | align: 65536]
  float* galign = out + B_*D_;            // holds G first, overwritten with align

  const size_t W1_N   = (size_t)D_*D_;      // 1M
  const size_t needed = W1_N*2 + (65536 + 32 + 2048 + 32768) * sizeof(float);

  if (ws_size >= needed) {
    unsigned short* w1t = (unsigned short*)d_ws;                   // 2 MB (fragment-major)
    float* fws   = (float*)(w1t + W1_N);
    float* e_buf = fws;                     // 65536
    float* tdot  = fws + 65536;             // 32
    float* v     = fws + 65568;             // 2048
    float* c     = fws + 67616;             // 32768

    hipMemsetAsync(e_buf, 0, 65536 * sizeof(float), stream);
    hipMemsetAsync(c, 0, 32768 * sizeof(float), stream);

    hipFuncSetAttribute(reinterpret_cast<const void*>(k2gt),
                        hipFuncAttributeMaxDynamicSharedMemorySize, 16384);

    k_pack_w1<<<512, 256, 0, stream>>>(W1, w1t);
    k0_tdot<<<32, 256, 0, stream>>>(h_t, Wmap, bmap, tdot);
    k2gt<<<2048, 256, 16384, stream>>>(h_s, w1t, b1, W2, e_buf,
                                       aux, Wmap, noise, tdot, galign);
    k3a_vmax<<<8, 256, 0, stream>>>(e_buf, v);
    k3b_align<<<32, 256, 0, stream>>>(e_buf, v, galign);
    k4_ctx_f32<<<2048, 256, 0, stream>>>(h_s, galign, c);
    k5_out<<<8192, 256, 0, stream>>>(c, h_t, Wout, out);
  } else {
    float* ws    = (float*)d_ws;
    float* e_buf = ws;                      // 65536
    float* tdot  = ws + 65536;              // 32
    float* v     = ws + 65568;              // 2048
    float* c     = ws + 67616;              // 32768

    hipMemsetAsync(e_buf, 0, 65536 * sizeof(float), stream);
    hipMemsetAsync(c, 0, 32768 * sizeof(float), stream);

    k0_tdot<<<32, 256, 0, stream>>>(h_t, Wmap, bmap, tdot);
    k1_gate<<<16384, 256, 0, stream>>>(aux, Wmap, noise, tdot, galign);
    k2_egemm_f32<<<4096, 256, 0, stream>>>(h_s, W1, b1, W2, e_buf);
    k3a_vmax<<<8, 256, 0, stream>>>(e_buf, v);
    k3b_align<<<32, 256, 0, stream>>>(e_buf, v, galign);
    k4_ctx_f32<<<2048, 256, 0, stream>>>(h_s, galign, c);
    k5_out<<<8192, 256, 0, stream>>>(c, h_t, Wout, out);
  }
}